// Round 1
// baseline (266.464 us; speedup 1.0000x reference)
//
#include <hip/hip_runtime.h>
#include <hip/hip_bf16.h>

typedef __bf16 bf16x8 __attribute__((ext_vector_type(8)));
typedef float  f32x4  __attribute__((ext_vector_type(4)));

#define B_  32
#define J_  143
#define F_  120
#define D_  256
#define L_  512
#define C_  13

// ---------------- prep: base = z@W_latent + b_latent ; W1T bf16 ; W2T bf16 (padded 16) --------
__global__ __launch_bounds__(256) void prep_kernel(
    const float* __restrict__ z, const float* __restrict__ W_latent,
    const float* __restrict__ b_latent, const float* __restrict__ W1,
    const float* __restrict__ W2,
    float* __restrict__ base, unsigned short* __restrict__ W1T,
    unsigned short* __restrict__ W2T) {
  const int t = threadIdx.x;
  const int bid = blockIdx.x;
  if (bid < B_) {
    float acc = 0.f;
    for (int k = 0; k < L_; ++k)
      acc = __builtin_fmaf(z[bid * L_ + k], W_latent[k * D_ + t], acc);
    base[bid * D_ + t] = acc + b_latent[t];
  } else if (bid < B_ + D_) {
    const int k = bid - B_;
    // W1T[n][k] = W1[k][n]
    W1T[t * D_ + k] = __builtin_bit_cast(unsigned short, (__bf16)W1[k * D_ + t]);
  } else {
    // W2T[c][k] = W2[k][c], c padded to 16 with zeros
    for (int c = 0; c < 16; ++c) {
      float v = (c < C_) ? W2[t * C_ + c] : 0.f;
      W2T[c * D_ + t] = __builtin_bit_cast(unsigned short, (__bf16)v);
    }
  }
}

// ---------------- exact GELU: 0.5 x (1+erf(x/sqrt(2))), A&S 7.1.26 erf ----------------
__device__ __forceinline__ float gelu_exact(float x) {
  float xs = x * 0.7071067811865476f;
  float ax = __builtin_fabsf(xs);
  float t  = __builtin_amdgcn_rcpf(__builtin_fmaf(0.3275911f, ax, 1.0f));
  float p  = __builtin_fmaf(1.061405429f, t, -1.453152027f);
  p = __builtin_fmaf(p, t, 1.421413741f);
  p = __builtin_fmaf(p, t, -0.284496736f);
  p = __builtin_fmaf(p, t, 0.254829592f);
  p = p * t;
  float e  = __expf(-ax * ax);
  float er = __builtin_fmaf(-p, e, 1.0f);
  er = (xs < 0.f) ? -er : er;
  return 0.5f * x * (1.0f + er);
}

// ---------------- main fused kernel: one block per (b,j) -----------------------------
__global__ __launch_bounds__(256, 2) void main_kernel(
    const float* __restrict__ joint_emb, const float* __restrict__ frame_emb,
    const float* __restrict__ ln_g, const float* __restrict__ ln_b,
    const float* __restrict__ b1, const float* __restrict__ b2,
    const float* __restrict__ base, const unsigned short* __restrict__ W1T,
    const unsigned short* __restrict__ W2T, float* __restrict__ out) {
  __shared__ __align__(16) unsigned char Bl[32768];   // W1T pass chunk, 64 rows x 256 k bf16, XOR-swizzled
  __shared__ __align__(16) unsigned char H2[16384];   // gelu output chunk, 128 rows x 64 cols bf16, swizzled
  __shared__ float outl[16 * 132];                    // out accum [c][f] padded
  __shared__ float cvec[D_], gml[D_], btl[D_], b1l[D_];

  const int tid  = threadIdx.x;
  const int lane = tid & 63;
  const int wave = tid >> 6;
  const int lrow = lane & 15;
  const int lgrp = lane >> 4;

  const int bj = blockIdx.x;
  const int b  = bj / J_;
  const int j  = bj - b * J_;

  cvec[tid] = base[b * D_ + tid] + joint_emb[j * D_ + tid];
  gml[tid]  = ln_g[tid];
  btl[tid]  = ln_b[tid];
  b1l[tid]  = b1[tid];
  __syncthreads();

  // ---- phase 1: hidden + LayerNorm, packed directly into MFMA A-fragments (in regs) ----
  bf16x8 A[2][8];
  #pragma unroll
  for (int mf = 0; mf < 2; ++mf) {
    const int row = wave * 32 + mf * 16 + lrow;       // 0..127
    const int f   = row < F_ ? row : F_ - 1;          // clamp pad rows (discarded at write)
    const float* fer = frame_emb + f * D_;
    float hid[64];
    float sum = 0.f, sq = 0.f;
    #pragma unroll
    for (int s = 0; s < 8; ++s) {
      const int k0 = s * 32 + lgrp * 8;
      float4 v0 = *(const float4*)(fer + k0);
      float4 v1 = *(const float4*)(fer + k0 + 4);
      float4 c0 = *(const float4*)(cvec + k0);
      float4 c1 = *(const float4*)(cvec + k0 + 4);
      float hv[8];
      hv[0] = v0.x + c0.x; hv[1] = v0.y + c0.y; hv[2] = v0.z + c0.z; hv[3] = v0.w + c0.w;
      hv[4] = v1.x + c1.x; hv[5] = v1.y + c1.y; hv[6] = v1.z + c1.z; hv[7] = v1.w + c1.w;
      #pragma unroll
      for (int e = 0; e < 8; ++e) {
        hid[s * 8 + e] = hv[e];
        sum += hv[e];
        sq = __builtin_fmaf(hv[e], hv[e], sq);
      }
    }
    sum += __shfl_xor(sum, 16); sum += __shfl_xor(sum, 32);
    sq  += __shfl_xor(sq, 16);  sq  += __shfl_xor(sq, 32);
    const float mean = sum * (1.f / 256.f);
    const float var  = sq * (1.f / 256.f) - mean * mean;
    const float rstd = rsqrtf(var + 1e-5f);
    #pragma unroll
    for (int s = 0; s < 8; ++s) {
      const int k0 = s * 32 + lgrp * 8;
      bf16x8 af;
      #pragma unroll
      for (int e = 0; e < 8; ++e) {
        float nv = __builtin_fmaf((hid[s * 8 + e] - mean) * rstd, gml[k0 + e], btl[k0 + e]);
        af[e] = (__bf16)nv;
      }
      A[mf][s] = af;
    }
  }

  f32x4 acc2[2] = {};   // GEMM2 accumulator, persists across passes

  // ---- pass loop: 4 x 64 output columns of GEMM1 ----
  for (int p = 0; p < 4; ++p) {
    __syncthreads();
    // stage W1T rows [p*64, p*64+64) into Bl with (row&15)<<4 XOR swizzle
    #pragma unroll
    for (int i = 0; i < 8; ++i) {
      const int c    = wave * 8 + i;
      const int row  = c * 2 + (lane >> 5);
      const int colb = (lane & 31) * 16;
      uint4 v = *(const uint4*)((const unsigned char*)W1T + (p * 64 + row) * 512 + colb);
      *(uint4*)(Bl + row * 512 + (colb ^ ((row & 15) << 4))) = v;
    }
    __syncthreads();

    // GEMM1: per wave 32 rows x 64 cols, K=256
    f32x4 acc[2][4] = {};
    #pragma unroll
    for (int s = 0; s < 8; ++s) {
      bf16x8 bf[4];
      #pragma unroll
      for (int n = 0; n < 4; ++n) {
        const int rowb = n * 16 + lrow;
        const int cb   = s * 64 + lgrp * 16;
        bf[n] = *(const bf16x8*)(Bl + rowb * 512 + (cb ^ (lrow << 4)));
      }
      #pragma unroll
      for (int mf = 0; mf < 2; ++mf)
        #pragma unroll
        for (int n = 0; n < 4; ++n)
          acc[mf][n] = __builtin_amdgcn_mfma_f32_16x16x32_bf16(A[mf][s], bf[n], acc[mf][n], 0, 0, 0);
    }

    // bias + exact gelu -> H2 (bf16, swizzled), wave-private rows
    #pragma unroll
    for (int mf = 0; mf < 2; ++mf) {
      #pragma unroll
      for (int n = 0; n < 4; ++n) {
        const float bb = b1l[p * 64 + n * 16 + lrow];
        #pragma unroll
        for (int r = 0; r < 4; ++r) {
          const int row  = wave * 32 + mf * 16 + lgrp * 4 + r;
          const int col2 = (n * 16 + lrow) * 2;
          const float g  = gelu_exact(acc[mf][n][r] + bb);
          *(__bf16*)(H2 + row * 128 + (col2 ^ ((row & 7) << 4))) = (__bf16)g;
        }
      }
    }

    // GEMM2 partial (wave reads only its own rows -> no barrier needed)
    #pragma unroll
    for (int q = 0; q < 2; ++q) {
      const bf16x8 b2f = *(const bf16x8*)((const unsigned char*)W2T + lrow * 512 + ((p * 2 + q) * 32 + lgrp * 8) * 2);
      #pragma unroll
      for (int mf2 = 0; mf2 < 2; ++mf2) {
        const int row = wave * 32 + mf2 * 16 + lrow;
        const int cb  = q * 64 + lgrp * 16;
        const bf16x8 a2 = *(const bf16x8*)(H2 + row * 128 + (cb ^ ((row & 7) << 4)));
        acc2[mf2] = __builtin_amdgcn_mfma_f32_16x16x32_bf16(a2, b2f, acc2[mf2], 0, 0, 0);
      }
    }
  }

  // ---- epilogue: acc2 -> out_lds[c][f] -> coalesced global write (b,j,c,f) ----
  #pragma unroll
  for (int mf2 = 0; mf2 < 2; ++mf2) {
    #pragma unroll
    for (int r = 0; r < 4; ++r) {
      const int frow = wave * 32 + mf2 * 16 + lgrp * 4 + r;
      outl[lrow * 132 + frow] = acc2[mf2][r];
    }
  }
  __syncthreads();
  const int obase = bj * C_ * F_;
  for (int idx = tid; idx < C_ * F_; idx += 256) {
    const int c = idx / F_;
    const int f = idx - c * F_;
    out[obase + idx] = outl[c * 132 + f] + b2[c];
  }
}

extern "C" void kernel_launch(void* const* d_in, const int* in_sizes, int n_in,
                              void* d_out, int out_size, void* d_ws, size_t ws_size,
                              hipStream_t stream) {
  const float* z         = (const float*)d_in[0];
  const float* W_latent  = (const float*)d_in[1];
  const float* b_latent  = (const float*)d_in[2];
  const float* joint_emb = (const float*)d_in[3];
  const float* frame_emb = (const float*)d_in[4];
  const float* ln_g      = (const float*)d_in[5];
  const float* ln_b      = (const float*)d_in[6];
  const float* W1        = (const float*)d_in[7];
  const float* b1        = (const float*)d_in[8];
  const float* W2        = (const float*)d_in[9];
  const float* b2        = (const float*)d_in[10];
  float* out = (float*)d_out;

  char* ws = (char*)d_ws;
  float*          base = (float*)ws;                      // 32 KB
  unsigned short* W1T  = (unsigned short*)(ws + 32768);   // 128 KB
  unsigned short* W2T  = (unsigned short*)(ws + 32768 + 131072); // 8 KB

  prep_kernel<<<B_ + D_ + 1, 256, 0, stream>>>(z, W_latent, b_latent, W1, W2, base, W1T, W2T);
  main_kernel<<<B_ * J_, 256, 0, stream>>>(joint_emb, frame_emb, ln_g, ln_b, b1, b2,
                                           base, W1T, W2T, out);
}

// Round 2
// 163.952 us; speedup vs baseline: 1.6253x; 1.6253x over previous
//
#include <hip/hip_runtime.h>
#include <hip/hip_bf16.h>

typedef __bf16 bf16x8 __attribute__((ext_vector_type(8)));
typedef float  f32x4  __attribute__((ext_vector_type(4)));

#define B_  32
#define J_  143
#define F_  120
#define D_  256
#define L_  512
#define C_  13
#define M_  4576      // B_*J_
#define MP_ 4736      // padded rows (37*128), fe rows live at 4576..4695
#define FE0 4576
#define NK  768       // K = [hi(256) | lo(256) | hi(256)]
#define NN  384       // N = [Wg1c(256) | feT(120) | pad(8)]

static __device__ __forceinline__ unsigned short bits(__bf16 h) {
  return __builtin_bit_cast(unsigned short, h);
}

// tanh-GELU: x*sigmoid(1.5957691x + 0.0713548x^3); max |err| vs exact ~2e-4
__device__ __forceinline__ float gelu_t(float x) {
  float x2 = x * x;
  float e  = __expf(x * __builtin_fmaf(x2, -0.07135481283f, -1.5957691216f));
  return x * __builtin_amdgcn_rcpf(1.0f + e);
}

// ---------- prep0: base = z @ W_latent + b_latent (32 x 256, K=512) ----------
__global__ __launch_bounds__(256) void prep0_kernel(
    const float* __restrict__ z, const float* __restrict__ Wl,
    const float* __restrict__ bl, float* __restrict__ base) {
  __shared__ float zs[L_];
  const int t = threadIdx.x, b = blockIdx.x;
  zs[t]       = z[b * L_ + t];
  zs[t + 256] = z[b * L_ + t + 256];
  __syncthreads();
  float acc = 0.f;
  #pragma unroll 8
  for (int k = 0; k < L_; ++k) acc = __builtin_fmaf(zs[k], Wl[k * D_ + t], acc);
  base[b * D_ + t] = acc + bl[t];
}

// ---------- prep1: build BT (hi|hi|lo rows), bW1, Sfe, Sfe2, W2T -------------
// grid 400: n<256 -> Wg1c col; 256..375 -> fe row; 376..383 -> zero; 384..399 -> W2T
__global__ __launch_bounds__(256) void prep1_kernel(
    const float* __restrict__ W1, const float* __restrict__ gamma,
    const float* __restrict__ beta, const float* __restrict__ b1,
    const float* __restrict__ frame_emb, const float* __restrict__ W2,
    unsigned short* __restrict__ BT, float* __restrict__ bW1,
    float* __restrict__ Sfe, float* __restrict__ Sfe2,
    unsigned short* __restrict__ W2T) {
  __shared__ float red[256];
  const int t = threadIdx.x, n = blockIdx.x;
  if (n < 256) {
    const float w1v = W1[t * D_ + n];
    const float wg = gamma[t] * w1v;
    const float wb = beta[t] * w1v;
    red[t] = wg; __syncthreads();
    for (int o = 128; o > 0; o >>= 1) { if (t < o) red[t] += red[t + o]; __syncthreads(); }
    const float cs = red[0]; __syncthreads();
    red[t] = wb; __syncthreads();
    for (int o = 128; o > 0; o >>= 1) { if (t < o) red[t] += red[t + o]; __syncthreads(); }
    if (t == 0) bW1[n] = red[0] + b1[n];
    const float m = __builtin_fmaf(cs, -1.f / 256.f, wg);
    const __bf16 hi = (__bf16)m;
    const __bf16 lo = (__bf16)(m - (float)hi);
    BT[n * NK + t]       = bits(hi);
    BT[n * NK + 256 + t] = bits(hi);
    BT[n * NK + 512 + t] = bits(lo);
  } else if (n < 376) {
    const int f = n - 256;
    const float v = frame_emb[f * D_ + t];
    red[t] = v; __syncthreads();
    for (int o = 128; o > 0; o >>= 1) { if (t < o) red[t] += red[t + o]; __syncthreads(); }
    if (t == 0) Sfe[f] = red[0];
    __syncthreads();
    red[t] = v * v; __syncthreads();
    for (int o = 128; o > 0; o >>= 1) { if (t < o) red[t] += red[t + o]; __syncthreads(); }
    if (t == 0) Sfe2[f] = red[0];
    const __bf16 hi = (__bf16)v;
    const __bf16 lo = (__bf16)(v - (float)hi);
    BT[n * NK + t]       = bits(hi);
    BT[n * NK + 256 + t] = bits(hi);
    BT[n * NK + 512 + t] = bits(lo);
  } else if (n < 384) {
    BT[n * NK + t] = 0; BT[n * NK + 256 + t] = 0; BT[n * NK + 512 + t] = 0;
  } else {
    const int c = n - 384;
    const float v = (c < C_) ? W2[t * C_ + c] : 0.f;
    W2T[c * D_ + t] = bits((__bf16)v);
  }
}

// ---------- a2: build A rows (c = base+joint for bj; fe rows; zero pad), Sc, Sc2 ----
__global__ __launch_bounds__(64) void a2_kernel(
    const float* __restrict__ base, const float* __restrict__ joint,
    const float* __restrict__ fe, unsigned short* __restrict__ Abf,
    float* __restrict__ Sc, float* __restrict__ Sc2) {
  const int r = blockIdx.x, lane = threadIdx.x;
  float c[4] = {0.f, 0.f, 0.f, 0.f};
  if (r < M_) {
    const int b = r / J_, j = r - b * J_;
    const float4 b4 = ((const float4*)base)[b * 64 + lane];
    const float4 j4 = ((const float4*)joint)[j * 64 + lane];
    c[0] = b4.x + j4.x; c[1] = b4.y + j4.y; c[2] = b4.z + j4.z; c[3] = b4.w + j4.w;
  } else if (r < FE0 + F_) {
    const float4 f4 = ((const float4*)fe)[(r - FE0) * 64 + lane];
    c[0] = f4.x; c[1] = f4.y; c[2] = f4.z; c[3] = f4.w;
  }
  ushort4 h4, l4;
  float sum = 0.f, sq = 0.f;
  unsigned short hh[4], ll[4];
  #pragma unroll
  for (int e = 0; e < 4; ++e) {
    const __bf16 h = (__bf16)c[e];
    hh[e] = bits(h);
    ll[e] = bits((__bf16)(c[e] - (float)h));
    sum += c[e];
    sq = __builtin_fmaf(c[e], c[e], sq);
  }
  h4.x = hh[0]; h4.y = hh[1]; h4.z = hh[2]; h4.w = hh[3];
  l4.x = ll[0]; l4.y = ll[1]; l4.z = ll[2]; l4.w = ll[3];
  *(ushort4*)(Abf + (size_t)r * NK + lane * 4)       = h4;
  *(ushort4*)(Abf + (size_t)r * NK + 256 + lane * 4) = l4;
  *(ushort4*)(Abf + (size_t)r * NK + 512 + lane * 4) = h4;
  #pragma unroll
  for (int m = 1; m < 64; m <<= 1) { sum += __shfl_xor(sum, m); sq += __shfl_xor(sq, m); }
  if (lane == 0) { Sc[r] = sum; Sc2[r] = sq; }
}

// ---------- gemmB: PX[MP_ x NN] = A(MP_ x NK) @ B(NK x NN), bf16 hi/lo exact ----
__global__ __launch_bounds__(256) void gemmB_kernel(
    const unsigned short* __restrict__ Abf, const unsigned short* __restrict__ BT,
    float* __restrict__ PX) {
  const int tid = threadIdx.x, lane = tid & 63, wave = tid >> 6;
  const int lrow = lane & 15, lgrp = lane >> 4;
  const int rb = blockIdx.x / 3, cb = blockIdx.x % 3;
  const int rowbase = rb * 128 + wave * 32;
  const int colbase = cb * 128;
  f32x4 acc[2][8] = {};
  const unsigned short* Ap0 = Abf + (size_t)(rowbase + lrow) * NK + lgrp * 8;
  const unsigned short* Ap1 = Ap0 + 16 * NK;
  const unsigned short* Bp  = BT + (size_t)(colbase + lrow) * NK + lgrp * 8;
  #pragma unroll 4
  for (int s = 0; s < 24; ++s) {
    const int k0 = s * 32;
    const bf16x8 a0 = *(const bf16x8*)(Ap0 + k0);
    const bf16x8 a1 = *(const bf16x8*)(Ap1 + k0);
    #pragma unroll
    for (int nf = 0; nf < 8; ++nf) {
      const bf16x8 bb = *(const bf16x8*)(Bp + (size_t)nf * 16 * NK + k0);
      acc[0][nf] = __builtin_amdgcn_mfma_f32_16x16x32_bf16(a0, bb, acc[0][nf], 0, 0, 0);
      acc[1][nf] = __builtin_amdgcn_mfma_f32_16x16x32_bf16(a1, bb, acc[1][nf], 0, 0, 0);
    }
  }
  #pragma unroll
  for (int mf = 0; mf < 2; ++mf)
    #pragma unroll
    for (int nf = 0; nf < 8; ++nf)
      #pragma unroll
      for (int r4 = 0; r4 < 4; ++r4)
        PX[(size_t)(rowbase + mf * 16 + lgrp * 4 + r4) * NN + colbase + nf * 16 + lrow] =
            acc[mf][nf][r4];
}

// ---------- mainC: u = rstd*(P1'+P2') + bW1; gelu; GEMM2; transpose-write ----
__global__ __launch_bounds__(256, 3) void mainC_kernel(
    const float* __restrict__ PX, const float* __restrict__ bW1,
    const float* __restrict__ Sc, const float* __restrict__ Sc2,
    const float* __restrict__ Sfe, const float* __restrict__ Sfe2,
    const unsigned short* __restrict__ W2T, const float* __restrict__ b2,
    float* __restrict__ out) {
  __shared__ float outl[16 * 132];
  const int tid = threadIdx.x, lane = tid & 63, wave = tid >> 6;
  const int lrow = lane & 15, lgrp = lane >> 4;
  const int bj = blockIdx.x;

  const float Scv = Sc[bj], Sc2v = Sc2[bj];
  const int r0 = wave * 32 + lrow;
  const int f0 = r0 < F_ ? r0 : F_ - 1;
  const int r1 = r0 + 16;
  const int f1 = r1 < F_ ? r1 : F_ - 1;
  const float X0 = PX[(size_t)bj * NN + 256 + f0];
  const float X1 = PX[(size_t)bj * NN + 256 + f1];
  const float mu0 = (Scv + Sfe[f0]) * (1.f / 256.f);
  const float mu1 = (Scv + Sfe[f1]) * (1.f / 256.f);
  const float ms0 = __builtin_fmaf(2.f, X0, Sc2v + Sfe2[f0]) * (1.f / 256.f);
  const float ms1 = __builtin_fmaf(2.f, X1, Sc2v + Sfe2[f1]) * (1.f / 256.f);
  const float rstd0 = rsqrtf(ms0 - mu0 * mu0 + 1e-5f);
  const float rstd1 = rsqrtf(ms1 - mu1 * mu1 + 1e-5f);

  const float* P1p = PX + (size_t)bj * NN;
  const float* P20 = PX + (size_t)(FE0 + f0) * NN;
  const float* P21 = PX + (size_t)(FE0 + f1) * NN;

  f32x4 acc2[2] = {};
  #pragma unroll
  for (int s = 0; s < 8; ++s) {
    const int n0 = s * 32 + lgrp * 8;
    const bf16x8 w2f = *(const bf16x8*)(W2T + (size_t)lrow * D_ + n0);
    const float4 p1a = *(const float4*)(P1p + n0);
    const float4 p1b = *(const float4*)(P1p + n0 + 4);
    const float4 bwa = *(const float4*)(bW1 + n0);
    const float4 bwb = *(const float4*)(bW1 + n0 + 4);
    const float4 qa  = *(const float4*)(P20 + n0);
    const float4 qb  = *(const float4*)(P20 + n0 + 4);
    const float4 ra  = *(const float4*)(P21 + n0);
    const float4 rb  = *(const float4*)(P21 + n0 + 4);
    const float p1v[8] = {p1a.x, p1a.y, p1a.z, p1a.w, p1b.x, p1b.y, p1b.z, p1b.w};
    const float bwv[8] = {bwa.x, bwa.y, bwa.z, bwa.w, bwb.x, bwb.y, bwb.z, bwb.w};
    const float q0v[8] = {qa.x, qa.y, qa.z, qa.w, qb.x, qb.y, qb.z, qb.w};
    const float q1v[8] = {ra.x, ra.y, ra.z, ra.w, rb.x, rb.y, rb.z, rb.w};
    bf16x8 af0, af1;
    #pragma unroll
    for (int e = 0; e < 8; ++e) {
      const float u0 = __builtin_fmaf(rstd0, p1v[e] + q0v[e], bwv[e]);
      const float u1 = __builtin_fmaf(rstd1, p1v[e] + q1v[e], bwv[e]);
      af0[e] = (__bf16)gelu_t(u0);
      af1[e] = (__bf16)gelu_t(u1);
    }
    acc2[0] = __builtin_amdgcn_mfma_f32_16x16x32_bf16(af0, w2f, acc2[0], 0, 0, 0);
    acc2[1] = __builtin_amdgcn_mfma_f32_16x16x32_bf16(af1, w2f, acc2[1], 0, 0, 0);
  }

  #pragma unroll
  for (int mf = 0; mf < 2; ++mf)
    #pragma unroll
    for (int r4 = 0; r4 < 4; ++r4) {
      const int frow = wave * 32 + mf * 16 + lgrp * 4 + r4;
      outl[lrow * 132 + frow] = acc2[mf][r4];
    }
  __syncthreads();
  const int obase = bj * C_ * F_;
  for (int idx = tid; idx < C_ * F_; idx += 256) {
    const int c = idx / F_;
    const int f = idx - c * F_;
    out[obase + idx] = outl[c * 132 + f] + b2[c];
  }
}

extern "C" void kernel_launch(void* const* d_in, const int* in_sizes, int n_in,
                              void* d_out, int out_size, void* d_ws, size_t ws_size,
                              hipStream_t stream) {
  const float* z         = (const float*)d_in[0];
  const float* W_latent  = (const float*)d_in[1];
  const float* b_latent  = (const float*)d_in[2];
  const float* joint_emb = (const float*)d_in[3];
  const float* frame_emb = (const float*)d_in[4];
  const float* ln_g      = (const float*)d_in[5];
  const float* ln_b      = (const float*)d_in[6];
  const float* W1        = (const float*)d_in[7];
  const float* b1        = (const float*)d_in[8];
  const float* W2        = (const float*)d_in[9];
  const float* b2        = (const float*)d_in[10];
  float* out = (float*)d_out;

  char* ws = (char*)d_ws;
  float*          base = (float*)(ws + 0);              // 32 KB
  unsigned short* W2T  = (unsigned short*)(ws + 32768); // 8 KB
  float*          bW1  = (float*)(ws + 40960);          // 1 KB
  float*          Sfe  = (float*)(ws + 41984);          // 0.5 KB
  float*          Sfe2 = (float*)(ws + 42496);          // 0.5 KB
  float*          Sc   = (float*)(ws + 43008);          // 18.5 KB
  float*          Sc2  = (float*)(ws + 61952);          // 18.5 KB
  unsigned short* BT   = (unsigned short*)(ws + 81920); // 576 KB
  unsigned short* Abf  = (unsigned short*)(ws + 1048576);   // 7.0 MB
  float*          PX   = (float*)(ws + 8388608);            // 7.0 MB

  prep0_kernel<<<B_, 256, 0, stream>>>(z, W_latent, b_latent, base);
  prep1_kernel<<<400, 256, 0, stream>>>(W1, ln_g, ln_b, b1, frame_emb, W2,
                                        BT, bW1, Sfe, Sfe2, W2T);
  a2_kernel<<<MP_, 64, 0, stream>>>(base, joint_emb, frame_emb, Abf, Sc, Sc2);
  gemmB_kernel<<<111, 256, 0, stream>>>(Abf, BT, PX);
  mainC_kernel<<<M_, 256, 0, stream>>>(PX, bW1, Sc, Sc2, Sfe, Sfe2, W2T, b2, out);
}

// Round 3
// 127.962 us; speedup vs baseline: 2.0824x; 1.2813x over previous
//
#include <hip/hip_runtime.h>
#include <hip/hip_bf16.h>

typedef __bf16 bf16x8 __attribute__((ext_vector_type(8)));
typedef float  f32x4  __attribute__((ext_vector_type(4)));

#define B_  32
#define J_  143
#define F_  120
#define D_  256
#define L_  512
#define C_  13
#define M_  4576      // B_*J_
#define MP_ 4736      // padded rows (74*64), fe rows live at 4576..4695
#define FE0 4576
#define NK  768       // K = [hi(256) | lo(256) | hi(256)]
#define NN  384       // N = [Wg1c(256) | feT(120) | pad(8)]

static __device__ __forceinline__ unsigned short bits(__bf16 h) {
  return __builtin_bit_cast(unsigned short, h);
}

// tanh-GELU with ln2 folded: x * rcp(1 + exp2(x*(c1 + c2*x^2)))
__device__ __forceinline__ float gelu_t(float x) {
  float x2 = x * x;
  float t  = x * __builtin_fmaf(x2, -0.1029432f, -2.3022082f);
  float e  = __builtin_amdgcn_exp2f(t);
  return x * __builtin_amdgcn_rcpf(1.0f + e);
}

// ---------- prepAll: [0,32) base=z@Wl+bl ; [32,288) BT cols ; [288,408) fe rows ; pads; W2T ----
__global__ __launch_bounds__(256) void prepAll_kernel(
    const float* __restrict__ z, const float* __restrict__ Wl,
    const float* __restrict__ bl, const float* __restrict__ W1,
    const float* __restrict__ gamma, const float* __restrict__ beta,
    const float* __restrict__ b1, const float* __restrict__ frame_emb,
    const float* __restrict__ W2,
    float* __restrict__ base, unsigned short* __restrict__ BT,
    float* __restrict__ bW1, float* __restrict__ Sfe, float* __restrict__ Sfe2,
    unsigned short* __restrict__ W2T) {
  const int t = threadIdx.x, bid = blockIdx.x;
  const int lane = t & 63, wv = t >> 6;
  __shared__ float zs[L_];
  __shared__ float ra[4], rb[4];
  if (bid < 32) {
    zs[t]       = z[bid * L_ + t];
    zs[t + 256] = z[bid * L_ + t + 256];
    __syncthreads();
    float acc = 0.f;
    #pragma unroll 8
    for (int k = 0; k < L_; ++k) acc = __builtin_fmaf(zs[k], Wl[k * D_ + t], acc);
    base[bid * D_ + t] = acc + bl[t];
    return;
  }
  const int n = bid - 32;
  if (n < 256) {
    const float w1v = W1[t * D_ + n];
    float a = gamma[t] * w1v;
    float b = beta[t] * w1v;
    const float wg = a;
    #pragma unroll
    for (int m = 1; m < 64; m <<= 1) { a += __shfl_xor(a, m); b += __shfl_xor(b, m); }
    if (lane == 0) { ra[wv] = a; rb[wv] = b; }
    __syncthreads();
    const float cs = ra[0] + ra[1] + ra[2] + ra[3];
    if (t == 0) bW1[n] = rb[0] + rb[1] + rb[2] + rb[3] + b1[n];
    const float m = __builtin_fmaf(cs, -1.f / 256.f, wg);
    const __bf16 hi = (__bf16)m;
    const __bf16 lo = (__bf16)(m - (float)hi);
    BT[n * NK + t]       = bits(hi);
    BT[n * NK + 256 + t] = bits(hi);
    BT[n * NK + 512 + t] = bits(lo);
  } else if (n < 376) {
    const int f = n - 256;
    const float v = frame_emb[f * D_ + t];
    float a = v, b = v * v;
    #pragma unroll
    for (int m = 1; m < 64; m <<= 1) { a += __shfl_xor(a, m); b += __shfl_xor(b, m); }
    if (lane == 0) { ra[wv] = a; rb[wv] = b; }
    __syncthreads();
    if (t == 0) {
      Sfe[f]  = ra[0] + ra[1] + ra[2] + ra[3];
      Sfe2[f] = rb[0] + rb[1] + rb[2] + rb[3];
    }
    const __bf16 hi = (__bf16)v;
    const __bf16 lo = (__bf16)(v - (float)hi);
    BT[n * NK + t]       = bits(hi);
    BT[n * NK + 256 + t] = bits(hi);
    BT[n * NK + 512 + t] = bits(lo);
  } else if (n < 384) {
    BT[n * NK + t] = 0; BT[n * NK + 256 + t] = 0; BT[n * NK + 512 + t] = 0;
  } else {
    const int c = n - 384;
    const float v = (c < C_) ? W2[t * C_ + c] : 0.f;
    W2T[c * D_ + t] = bits((__bf16)v);
  }
}

// ---------- a2: A rows (c=base+joint; fe rows; zero pad), Sc, Sc2 — 4 rows/block ----
__global__ __launch_bounds__(256) void a2_kernel(
    const float* __restrict__ base, const float* __restrict__ joint,
    const float* __restrict__ fe, unsigned short* __restrict__ Abf,
    float* __restrict__ Sc, float* __restrict__ Sc2) {
  const int lane = threadIdx.x & 63;
  const int r = blockIdx.x * 4 + (threadIdx.x >> 6);
  float c[4] = {0.f, 0.f, 0.f, 0.f};
  if (r < M_) {
    const int b = r / J_, j = r - b * J_;
    const float4 b4 = ((const float4*)base)[b * 64 + lane];
    const float4 j4 = ((const float4*)joint)[j * 64 + lane];
    c[0] = b4.x + j4.x; c[1] = b4.y + j4.y; c[2] = b4.z + j4.z; c[3] = b4.w + j4.w;
  } else if (r < FE0 + F_) {
    const float4 f4 = ((const float4*)fe)[(r - FE0) * 64 + lane];
    c[0] = f4.x; c[1] = f4.y; c[2] = f4.z; c[3] = f4.w;
  }
  ushort4 h4, l4;
  float sum = 0.f, sq = 0.f;
  unsigned short hh[4], ll[4];
  #pragma unroll
  for (int e = 0; e < 4; ++e) {
    const __bf16 h = (__bf16)c[e];
    hh[e] = bits(h);
    ll[e] = bits((__bf16)(c[e] - (float)h));
    sum += c[e];
    sq = __builtin_fmaf(c[e], c[e], sq);
  }
  h4.x = hh[0]; h4.y = hh[1]; h4.z = hh[2]; h4.w = hh[3];
  l4.x = ll[0]; l4.y = ll[1]; l4.z = ll[2]; l4.w = ll[3];
  *(ushort4*)(Abf + (size_t)r * NK + lane * 4)       = h4;
  *(ushort4*)(Abf + (size_t)r * NK + 256 + lane * 4) = l4;
  *(ushort4*)(Abf + (size_t)r * NK + 512 + lane * 4) = h4;
  #pragma unroll
  for (int m = 1; m < 64; m <<= 1) { sum += __shfl_xor(sum, m); sq += __shfl_xor(sq, m); }
  if (lane == 0) { Sc[r] = sum; Sc2[r] = sq; }
}

// ---------- gemmB: PX[MP_ x NN] = A @ B, 64x64 tiles, 444 blocks ----
__global__ __launch_bounds__(256) void gemmB_kernel(
    const unsigned short* __restrict__ Abf, const unsigned short* __restrict__ BT,
    float* __restrict__ PX) {
  const int tid = threadIdx.x, lane = tid & 63, wave = tid >> 6;
  const int lrow = lane & 15, lgrp = lane >> 4;
  const int rb = blockIdx.x / 6, cb = blockIdx.x % 6;
  const int rowbase = rb * 64 + wave * 16;
  const int colbase = cb * 64;
  f32x4 acc[4] = {};
  const unsigned short* Ap = Abf + (size_t)(rowbase + lrow) * NK + lgrp * 8;
  const unsigned short* Bp = BT + (size_t)(colbase + lrow) * NK + lgrp * 8;
  #pragma unroll 6
  for (int s = 0; s < 24; ++s) {
    const int k0 = s * 32;
    const bf16x8 a = *(const bf16x8*)(Ap + k0);
    #pragma unroll
    for (int nf = 0; nf < 4; ++nf) {
      const bf16x8 bb = *(const bf16x8*)(Bp + (size_t)nf * 16 * NK + k0);
      acc[nf] = __builtin_amdgcn_mfma_f32_16x16x32_bf16(a, bb, acc[nf], 0, 0, 0);
    }
  }
  #pragma unroll
  for (int nf = 0; nf < 4; ++nf)
    #pragma unroll
    for (int r4 = 0; r4 < 4; ++r4)
      PX[(size_t)(rowbase + lgrp * 4 + r4) * NN + colbase + nf * 16 + lrow] = acc[nf][r4];
}

// ---------- mainC: u = rstd*(P1+P2) + bW1; gelu; GEMM2; transpose-write ----
__global__ __launch_bounds__(256, 2) void mainC_kernel(
    const float* __restrict__ PX, const float* __restrict__ bW1,
    const float* __restrict__ Sc, const float* __restrict__ Sc2,
    const float* __restrict__ Sfe, const float* __restrict__ Sfe2,
    const unsigned short* __restrict__ W2T, const float* __restrict__ b2,
    float* __restrict__ out) {
  __shared__ float pc[256], bw[256], rstdl[128];
  __shared__ __align__(16) unsigned short w2l[4096];   // 16x256 bf16, XOR-swizzled
  __shared__ float outl[16 * 132];
  const int tid = threadIdx.x, lane = tid & 63, wave = tid >> 6;
  const int lrow = lane & 15, lgrp = lane >> 4;
  const int bj = blockIdx.x;
  const float* __restrict__ P1p = PX + (size_t)bj * NN;

  pc[tid] = P1p[tid];
  bw[tid] = bW1[tid];
  {
    const int r = tid >> 4;
    const int b0 = tid * 32;
    const int sb = b0 ^ ((r & 7) << 4);
    *(uint4*)((char*)w2l + sb)        = *(const uint4*)((const char*)W2T + b0);
    *(uint4*)((char*)w2l + (sb ^ 16)) = *(const uint4*)((const char*)W2T + b0 + 16);
  }
  if (tid < 128) {
    const int f = tid < F_ ? tid : F_ - 1;
    const float X = P1p[256 + f];
    const float mu = (Sc[bj] + Sfe[f]) * (1.f / 256.f);
    const float ms = __builtin_fmaf(2.f, X, Sc2[bj] + Sfe2[f]) * (1.f / 256.f);
    rstdl[tid] = rsqrtf(ms - mu * mu + 1e-5f);
  }
  __syncthreads();

  const int r0 = wave * 32 + lrow, r1 = r0 + 16;
  const int f0 = r0 < F_ ? r0 : F_ - 1;
  const int f1 = r1 < F_ ? r1 : F_ - 1;
  const float rstd0 = rstdl[r0], rstd1 = rstdl[r1];
  const float* __restrict__ P20 = PX + (size_t)(FE0 + f0) * NN;
  const float* __restrict__ P21 = PX + (size_t)(FE0 + f1) * NN;

  f32x4 acc2[2] = {};
  const int cc = lgrp * 8;
  float4 qa0 = *(const float4*)(P20 + cc), qa1 = *(const float4*)(P20 + cc + 4);
  float4 qb0 = *(const float4*)(P21 + cc), qb1 = *(const float4*)(P21 + cc + 4);
  #pragma unroll
  for (int s = 0; s < 8; ++s) {
    const int n0 = s * 32 + cc;
    float4 na0, na1, nb0, nb1;
    if (s < 7) {
      na0 = *(const float4*)(P20 + n0 + 32); na1 = *(const float4*)(P20 + n0 + 36);
      nb0 = *(const float4*)(P21 + n0 + 32); nb1 = *(const float4*)(P21 + n0 + 36);
    }
    const float4 pa = *(const float4*)(pc + n0), pb = *(const float4*)(pc + n0 + 4);
    const float4 ba = *(const float4*)(bw + n0), bb = *(const float4*)(bw + n0 + 4);
    const bf16x8 w2f = *(const bf16x8*)((const char*)w2l +
        ((lrow * 512 + n0 * 2) ^ ((lrow & 7) << 4)));
    const float pv[8] = {pa.x, pa.y, pa.z, pa.w, pb.x, pb.y, pb.z, pb.w};
    const float bv[8] = {ba.x, ba.y, ba.z, ba.w, bb.x, bb.y, bb.z, bb.w};
    const float q0v[8] = {qa0.x, qa0.y, qa0.z, qa0.w, qa1.x, qa1.y, qa1.z, qa1.w};
    const float q1v[8] = {qb0.x, qb0.y, qb0.z, qb0.w, qb1.x, qb1.y, qb1.z, qb1.w};
    bf16x8 af0, af1;
    #pragma unroll
    for (int e = 0; e < 8; ++e) {
      const float u0 = __builtin_fmaf(rstd0, pv[e] + q0v[e], bv[e]);
      const float u1 = __builtin_fmaf(rstd1, pv[e] + q1v[e], bv[e]);
      af0[e] = (__bf16)gelu_t(u0);
      af1[e] = (__bf16)gelu_t(u1);
    }
    acc2[0] = __builtin_amdgcn_mfma_f32_16x16x32_bf16(af0, w2f, acc2[0], 0, 0, 0);
    acc2[1] = __builtin_amdgcn_mfma_f32_16x16x32_bf16(af1, w2f, acc2[1], 0, 0, 0);
    qa0 = na0; qa1 = na1; qb0 = nb0; qb1 = nb1;
  }

  #pragma unroll
  for (int mf = 0; mf < 2; ++mf)
    #pragma unroll
    for (int r4 = 0; r4 < 4; ++r4) {
      const int frow = wave * 32 + mf * 16 + lgrp * 4 + r4;
      outl[lrow * 132 + frow] = acc2[mf][r4];
    }
  __syncthreads();
  const int obase = bj * C_ * F_;
  for (int idx = tid; idx < C_ * F_; idx += 256) {
    const int c = idx / F_;
    const int f = idx - c * F_;
    out[obase + idx] = outl[c * 132 + f] + b2[c];
  }
}

extern "C" void kernel_launch(void* const* d_in, const int* in_sizes, int n_in,
                              void* d_out, int out_size, void* d_ws, size_t ws_size,
                              hipStream_t stream) {
  const float* z         = (const float*)d_in[0];
  const float* W_latent  = (const float*)d_in[1];
  const float* b_latent  = (const float*)d_in[2];
  const float* joint_emb = (const float*)d_in[3];
  const float* frame_emb = (const float*)d_in[4];
  const float* ln_g      = (const float*)d_in[5];
  const float* ln_b      = (const float*)d_in[6];
  const float* W1        = (const float*)d_in[7];
  const float* b1        = (const float*)d_in[8];
  const float* W2        = (const float*)d_in[9];
  const float* b2        = (const float*)d_in[10];
  float* out = (float*)d_out;

  char* ws = (char*)d_ws;
  float*          base = (float*)(ws + 0);              // 32 KB
  unsigned short* W2T  = (unsigned short*)(ws + 32768); // 8 KB
  float*          bW1  = (float*)(ws + 40960);          // 1 KB
  float*          Sfe  = (float*)(ws + 41984);          // 0.5 KB
  float*          Sfe2 = (float*)(ws + 42496);          // 0.5 KB
  float*          Sc   = (float*)(ws + 43008);          // 18.5 KB
  float*          Sc2  = (float*)(ws + 61952);          // 18.5 KB
  unsigned short* BT   = (unsigned short*)(ws + 81920); // 576 KB
  unsigned short* Abf  = (unsigned short*)(ws + 1048576);   // 7.0 MB
  float*          PX   = (float*)(ws + 8388608);            // 7.0 MB

  prepAll_kernel<<<432, 256, 0, stream>>>(z, W_latent, b_latent, W1, ln_g, ln_b, b1,
                                          frame_emb, W2, base, BT, bW1, Sfe, Sfe2, W2T);
  a2_kernel<<<MP_ / 4, 256, 0, stream>>>(base, joint_emb, frame_emb, Abf, Sc, Sc2);
  gemmB_kernel<<<444, 256, 0, stream>>>(Abf, BT, PX);
  mainC_kernel<<<M_, 256, 0, stream>>>(PX, bW1, Sc, Sc2, Sfe, Sfe2, W2T, b2, out);
}

// Round 4
// 109.987 us; speedup vs baseline: 2.4227x; 1.1634x over previous
//
#include <hip/hip_runtime.h>
#include <hip/hip_bf16.h>

typedef __bf16 bf16x8 __attribute__((ext_vector_type(8)));
typedef float  f32x4  __attribute__((ext_vector_type(4)));

#define B_  32
#define J_  143
#define F_  120
#define D_  256
#define L_  512
#define C_  13
#define M_  4576      // B_*J_
#define MP_ 4736      // padded rows (74*64), fe rows live at 4576..4695
#define FE0 4576
#define NK  768       // K = [hi(256) | lo(256) | hi(256)]
#define NN  384       // N = [Wg1c(256) | feT(120) | pad(8)]

static __device__ __forceinline__ unsigned short bits(__bf16 h) {
  return __builtin_bit_cast(unsigned short, h);
}

// tanh-GELU with ln2 folded: x * rcp(1 + exp2(x*(c1 + c2*x^2)))
__device__ __forceinline__ float gelu_t(float x) {
  float x2 = x * x;
  float t  = x * __builtin_fmaf(x2, -0.1029432f, -2.3022082f);
  float e  = __builtin_amdgcn_exp2f(t);
  return x * __builtin_amdgcn_rcpf(1.0f + e);
}

// ---------- prepAll: [0,32) base=z@Wl+bl ; [32,288) BT cols ; [288,408) fe rows ; pads; W2T ----
__global__ __launch_bounds__(256) void prepAll_kernel(
    const float* __restrict__ z, const float* __restrict__ Wl,
    const float* __restrict__ bl, const float* __restrict__ W1,
    const float* __restrict__ gamma, const float* __restrict__ beta,
    const float* __restrict__ b1, const float* __restrict__ frame_emb,
    const float* __restrict__ W2,
    float* __restrict__ base, unsigned short* __restrict__ BT,
    float* __restrict__ bW1, float* __restrict__ Sfe, float* __restrict__ Sfe2,
    unsigned short* __restrict__ W2T) {
  const int t = threadIdx.x, bid = blockIdx.x;
  const int lane = t & 63, wv = t >> 6;
  __shared__ float zs[L_];
  __shared__ float ra[4], rb[4];
  if (bid < 32) {
    zs[t]       = z[bid * L_ + t];
    zs[t + 256] = z[bid * L_ + t + 256];
    __syncthreads();
    float acc = 0.f;
    #pragma unroll 8
    for (int k = 0; k < L_; ++k) acc = __builtin_fmaf(zs[k], Wl[k * D_ + t], acc);
    base[bid * D_ + t] = acc + bl[t];
    return;
  }
  const int n = bid - 32;
  if (n < 256) {
    const float w1v = W1[t * D_ + n];
    float a = gamma[t] * w1v;
    float b = beta[t] * w1v;
    const float wg = a;
    #pragma unroll
    for (int m = 1; m < 64; m <<= 1) { a += __shfl_xor(a, m); b += __shfl_xor(b, m); }
    if (lane == 0) { ra[wv] = a; rb[wv] = b; }
    __syncthreads();
    const float cs = ra[0] + ra[1] + ra[2] + ra[3];
    if (t == 0) bW1[n] = rb[0] + rb[1] + rb[2] + rb[3] + b1[n];
    const float m = __builtin_fmaf(cs, -1.f / 256.f, wg);
    const __bf16 hi = (__bf16)m;
    const __bf16 lo = (__bf16)(m - (float)hi);
    BT[n * NK + t]       = bits(hi);
    BT[n * NK + 256 + t] = bits(hi);
    BT[n * NK + 512 + t] = bits(lo);
  } else if (n < 376) {
    const int f = n - 256;
    const float v = frame_emb[f * D_ + t];
    float a = v, b = v * v;
    #pragma unroll
    for (int m = 1; m < 64; m <<= 1) { a += __shfl_xor(a, m); b += __shfl_xor(b, m); }
    if (lane == 0) { ra[wv] = a; rb[wv] = b; }
    __syncthreads();
    if (t == 0) {
      Sfe[f]  = ra[0] + ra[1] + ra[2] + ra[3];
      Sfe2[f] = rb[0] + rb[1] + rb[2] + rb[3];
    }
    const __bf16 hi = (__bf16)v;
    const __bf16 lo = (__bf16)(v - (float)hi);
    BT[n * NK + t]       = bits(hi);
    BT[n * NK + 256 + t] = bits(hi);
    BT[n * NK + 512 + t] = bits(lo);
  } else if (n < 384) {
    BT[n * NK + t] = 0; BT[n * NK + 256 + t] = 0; BT[n * NK + 512 + t] = 0;
  } else {
    const int c = n - 384;
    const float v = (c < C_) ? W2[t * C_ + c] : 0.f;
    W2T[c * D_ + t] = bits((__bf16)v);
  }
}

// ---------- a2: A rows (c=base+joint; fe rows; zero pad), Sc, Sc2 — 4 rows/block ----
__global__ __launch_bounds__(256) void a2_kernel(
    const float* __restrict__ base, const float* __restrict__ joint,
    const float* __restrict__ fe, unsigned short* __restrict__ Abf,
    float* __restrict__ Sc, float* __restrict__ Sc2) {
  const int lane = threadIdx.x & 63;
  const int r = blockIdx.x * 4 + (threadIdx.x >> 6);
  float c[4] = {0.f, 0.f, 0.f, 0.f};
  if (r < M_) {
    const int b = r / J_, j = r - b * J_;
    const float4 b4 = ((const float4*)base)[b * 64 + lane];
    const float4 j4 = ((const float4*)joint)[j * 64 + lane];
    c[0] = b4.x + j4.x; c[1] = b4.y + j4.y; c[2] = b4.z + j4.z; c[3] = b4.w + j4.w;
  } else if (r < FE0 + F_) {
    const float4 f4 = ((const float4*)fe)[(r - FE0) * 64 + lane];
    c[0] = f4.x; c[1] = f4.y; c[2] = f4.z; c[3] = f4.w;
  }
  ushort4 h4, l4;
  float sum = 0.f, sq = 0.f;
  unsigned short hh[4], ll[4];
  #pragma unroll
  for (int e = 0; e < 4; ++e) {
    const __bf16 h = (__bf16)c[e];
    hh[e] = bits(h);
    ll[e] = bits((__bf16)(c[e] - (float)h));
    sum += c[e];
    sq = __builtin_fmaf(c[e], c[e], sq);
  }
  h4.x = hh[0]; h4.y = hh[1]; h4.z = hh[2]; h4.w = hh[3];
  l4.x = ll[0]; l4.y = ll[1]; l4.z = ll[2]; l4.w = ll[3];
  *(ushort4*)(Abf + (size_t)r * NK + lane * 4)       = h4;
  *(ushort4*)(Abf + (size_t)r * NK + 256 + lane * 4) = l4;
  *(ushort4*)(Abf + (size_t)r * NK + 512 + lane * 4) = h4;
  #pragma unroll
  for (int m = 1; m < 64; m <<= 1) { sum += __shfl_xor(sum, m); sq += __shfl_xor(sq, m); }
  if (lane == 0) { Sc[r] = sum; Sc2[r] = sq; }
}

// ---------- gemmB: PX[MP_ x NN] = A @ B, 64x64 tiles; fe-panel also stored bf16 ----
__global__ __launch_bounds__(256) void gemmB_kernel(
    const unsigned short* __restrict__ Abf, const unsigned short* __restrict__ BT,
    float* __restrict__ PX, unsigned short* __restrict__ P2h) {
  const int tid = threadIdx.x, lane = tid & 63, wave = tid >> 6;
  const int lrow = lane & 15, lgrp = lane >> 4;
  const int rb = blockIdx.x / 6, cb = blockIdx.x % 6;
  const int rowbase = rb * 64 + wave * 16;
  const int colbase = cb * 64;
  f32x4 acc[4] = {};
  const unsigned short* Ap = Abf + (size_t)(rowbase + lrow) * NK + lgrp * 8;
  const unsigned short* Bp = BT + (size_t)(colbase + lrow) * NK + lgrp * 8;
  #pragma unroll 6
  for (int s = 0; s < 24; ++s) {
    const int k0 = s * 32;
    const bf16x8 a = *(const bf16x8*)(Ap + k0);
    #pragma unroll
    for (int nf = 0; nf < 4; ++nf) {
      const bf16x8 bb = *(const bf16x8*)(Bp + (size_t)nf * 16 * NK + k0);
      acc[nf] = __builtin_amdgcn_mfma_f32_16x16x32_bf16(a, bb, acc[nf], 0, 0, 0);
    }
  }
  #pragma unroll
  for (int nf = 0; nf < 4; ++nf)
    #pragma unroll
    for (int r4 = 0; r4 < 4; ++r4) {
      const int orow = rowbase + lgrp * 4 + r4;
      const int ocol = colbase + nf * 16 + lrow;
      const float v = acc[nf][r4];
      PX[(size_t)orow * NN + ocol] = v;
      const int fr = orow - FE0;
      if (fr >= 0 && fr < F_ && ocol < 256)
        P2h[fr * 256 + ocol] = bits((__bf16)v);
    }
}

// ---------- mainC: 2 bj per block; u = rstd*(P1+P2) + bW1; gelu; GEMM2; write ----
__global__ __launch_bounds__(256, 4) void mainC_kernel(
    const float* __restrict__ PX, const unsigned short* __restrict__ P2h,
    const float* __restrict__ bW1,
    const float* __restrict__ Sc, const float* __restrict__ Sc2,
    const float* __restrict__ Sfe, const float* __restrict__ Sfe2,
    const unsigned short* __restrict__ W2T, const float* __restrict__ b2,
    float* __restrict__ out) {
  __shared__ float pc[2][256], bw[256], rstdl[2][128];
  __shared__ __align__(16) unsigned short w2l[4096];   // 16x256 bf16, XOR-swizzled
  __shared__ float outl[16 * 133];
  const int tid = threadIdx.x, lane = tid & 63, wave = tid >> 6;
  const int lrow = lane & 15, lgrp = lane >> 4;
  const int bj0 = blockIdx.x * 2;

  #pragma unroll
  for (int q = 0; q < 2; ++q) pc[q][tid] = PX[(size_t)(bj0 + q) * NN + tid];
  bw[tid] = bW1[tid];
  {
    const int r = tid >> 4;
    const int b0 = tid * 32;
    const int sb = b0 ^ ((r & 7) << 4);
    *(uint4*)((char*)w2l + sb)        = *(const uint4*)((const char*)W2T + b0);
    *(uint4*)((char*)w2l + (sb ^ 16)) = *(const uint4*)((const char*)W2T + b0 + 16);
  }
  {
    const int q = tid >> 7;
    const int f = tid & 127;
    const int fc = f < F_ ? f : F_ - 1;
    const float X = PX[(size_t)(bj0 + q) * NN + 256 + fc];
    const float mu = (Sc[bj0 + q] + Sfe[fc]) * (1.f / 256.f);
    const float ms = __builtin_fmaf(2.f, X, Sc2[bj0 + q] + Sfe2[fc]) * (1.f / 256.f);
    rstdl[q][f] = rsqrtf(ms - mu * mu + 1e-5f);
  }
  __syncthreads();

  const int r0 = wave * 32 + lrow, r1 = r0 + 16;
  const int f0 = r0 < F_ ? r0 : F_ - 1;
  const int f1 = r1 < F_ ? r1 : F_ - 1;
  float rs0[2], rs1[2];
  #pragma unroll
  for (int q = 0; q < 2; ++q) { rs0[q] = rstdl[q][r0]; rs1[q] = rstdl[q][r1]; }
  const unsigned short* __restrict__ q0p = P2h + f0 * 256;
  const unsigned short* __restrict__ q1p = P2h + f1 * 256;

  f32x4 acc[2][2] = {};
  #pragma unroll
  for (int s = 0; s < 8; ++s) {
    const int n0 = s * 32 + lgrp * 8;
    const bf16x8 qh0 = *(const bf16x8*)(q0p + n0);
    const bf16x8 qh1 = *(const bf16x8*)(q1p + n0);
    const bf16x8 w2f = *(const bf16x8*)((const char*)w2l +
        ((lrow * 512 + n0 * 2) ^ ((lrow & 7) << 4)));
    float q0f[8], q1f[8], bv[8];
    #pragma unroll
    for (int e = 0; e < 8; ++e) { q0f[e] = (float)qh0[e]; q1f[e] = (float)qh1[e]; }
    const float4 ba = *(const float4*)(&bw[n0]);
    const float4 bb = *(const float4*)(&bw[n0 + 4]);
    bv[0] = ba.x; bv[1] = ba.y; bv[2] = ba.z; bv[3] = ba.w;
    bv[4] = bb.x; bv[5] = bb.y; bv[6] = bb.z; bv[7] = bb.w;
    #pragma unroll
    for (int q = 0; q < 2; ++q) {
      const float4 pa = *(const float4*)(&pc[q][n0]);
      const float4 pb = *(const float4*)(&pc[q][n0 + 4]);
      const float pv[8] = {pa.x, pa.y, pa.z, pa.w, pb.x, pb.y, pb.z, pb.w};
      bf16x8 af0, af1;
      #pragma unroll
      for (int e = 0; e < 8; ++e) {
        const float u0 = __builtin_fmaf(rs0[q], pv[e] + q0f[e], bv[e]);
        const float u1 = __builtin_fmaf(rs1[q], pv[e] + q1f[e], bv[e]);
        af0[e] = (__bf16)gelu_t(u0);
        af1[e] = (__bf16)gelu_t(u1);
      }
      acc[q][0] = __builtin_amdgcn_mfma_f32_16x16x32_bf16(af0, w2f, acc[q][0], 0, 0, 0);
      acc[q][1] = __builtin_amdgcn_mfma_f32_16x16x32_bf16(af1, w2f, acc[q][1], 0, 0, 0);
    }
  }

  #pragma unroll
  for (int q = 0; q < 2; ++q) {
    #pragma unroll
    for (int mf = 0; mf < 2; ++mf)
      #pragma unroll
      for (int r4 = 0; r4 < 4; ++r4) {
        const int frow = wave * 32 + mf * 16 + lgrp * 4 + r4;
        outl[lrow * 133 + frow] = acc[q][mf][r4];
      }
    __syncthreads();
    const int obase = (bj0 + q) * C_ * F_;
    for (int idx = tid; idx < C_ * F_; idx += 256) {
      const int c = idx / F_;
      const int f = idx - c * F_;
      out[obase + idx] = outl[c * 133 + f] + b2[c];
    }
    __syncthreads();
  }
}

extern "C" void kernel_launch(void* const* d_in, const int* in_sizes, int n_in,
                              void* d_out, int out_size, void* d_ws, size_t ws_size,
                              hipStream_t stream) {
  const float* z         = (const float*)d_in[0];
  const float* W_latent  = (const float*)d_in[1];
  const float* b_latent  = (const float*)d_in[2];
  const float* joint_emb = (const float*)d_in[3];
  const float* frame_emb = (const float*)d_in[4];
  const float* ln_g      = (const float*)d_in[5];
  const float* ln_b      = (const float*)d_in[6];
  const float* W1        = (const float*)d_in[7];
  const float* b1        = (const float*)d_in[8];
  const float* W2        = (const float*)d_in[9];
  const float* b2        = (const float*)d_in[10];
  float* out = (float*)d_out;

  char* ws = (char*)d_ws;
  float*          base = (float*)(ws + 0);              // 32 KB
  unsigned short* W2T  = (unsigned short*)(ws + 32768); // 8 KB
  float*          bW1  = (float*)(ws + 40960);          // 1 KB
  float*          Sfe  = (float*)(ws + 41984);          // 0.5 KB
  float*          Sfe2 = (float*)(ws + 42496);          // 0.5 KB
  float*          Sc   = (float*)(ws + 43008);          // 18.5 KB
  float*          Sc2  = (float*)(ws + 61952);          // 18.5 KB
  unsigned short* P2h  = (unsigned short*)(ws + 700416);// 60 KB (gap before Abf)
  unsigned short* BT   = (unsigned short*)(ws + 81920); // 576 KB
  unsigned short* Abf  = (unsigned short*)(ws + 1048576);   // 7.0 MB
  float*          PX   = (float*)(ws + 8388608);            // 7.0 MB

  prepAll_kernel<<<432, 256, 0, stream>>>(z, W_latent, b_latent, W1, ln_g, ln_b, b1,
                                          frame_emb, W2, base, BT, bW1, Sfe, Sfe2, W2T);
  a2_kernel<<<MP_ / 4, 256, 0, stream>>>(base, joint_emb, frame_emb, Abf, Sc, Sc2);
  gemmB_kernel<<<444, 256, 0, stream>>>(Abf, BT, PX, P2h);
  mainC_kernel<<<M_ / 2, 256, 0, stream>>>(PX, P2h, bW1, Sc, Sc2, Sfe, Sfe2, W2T, b2, out);
}

// Round 5
// 88.615 us; speedup vs baseline: 3.0070x; 1.2412x over previous
//
#include <hip/hip_runtime.h>
#include <hip/hip_bf16.h>

typedef __bf16 bf16x8 __attribute__((ext_vector_type(8)));
typedef float  f32x4  __attribute__((ext_vector_type(4)));

#define B_  32
#define J_  143
#define F_  120
#define D_  256
#define L_  512
#define C_  13
#define M_  4576      // B_*J_
#define MP_ 4736      // padded rows (74*64), fe rows live at 4576..4695
#define FE0 4576
#define NK  512       // K = [hi(256) | lo(256)]
#define NN  384       // N = [Wg1c(256) | feT(120) | pad(8)]

static __device__ __forceinline__ unsigned short bits(__bf16 h) {
  return __builtin_bit_cast(unsigned short, h);
}

// tanh-GELU with ln2 folded: x * rcp(1 + exp2(x*(c1 + c2*x^2)))
__device__ __forceinline__ float gelu_t(float x) {
  float x2 = x * x;
  float t  = x * __builtin_fmaf(x2, -0.1029432f, -2.3022082f);
  float e  = __builtin_amdgcn_exp2f(t);
  return x * __builtin_amdgcn_rcpf(1.0f + e);
}

// ---------- prepAll ----------
// bid<32: base=z@Wl+bl ; n=bid-32: [0,256) BT col; [256,376) fe row; [376,384) pad;
// [384,400) W2T row; 400: zerov
__global__ __launch_bounds__(256) void prepAll_kernel(
    const float* __restrict__ z, const float* __restrict__ Wl,
    const float* __restrict__ bl, const float* __restrict__ W1,
    const float* __restrict__ gamma, const float* __restrict__ beta,
    const float* __restrict__ b1, const float* __restrict__ frame_emb,
    const float* __restrict__ W2,
    float* __restrict__ base, unsigned short* __restrict__ BT,
    float* __restrict__ bW1, float* __restrict__ Sfe, float* __restrict__ Sfe2,
    unsigned short* __restrict__ W2T, float* __restrict__ zerov) {
  const int t = threadIdx.x, bid = blockIdx.x;
  const int lane = t & 63, wv = t >> 6;
  __shared__ float zs[L_];
  __shared__ float ra[4], rb[4];
  if (bid < 32) {
    zs[t]       = z[bid * L_ + t];
    zs[t + 256] = z[bid * L_ + t + 256];
    __syncthreads();
    float acc = 0.f;
    #pragma unroll 32
    for (int k = 0; k < L_; ++k) acc = __builtin_fmaf(zs[k], Wl[k * D_ + t], acc);
    base[bid * D_ + t] = acc + bl[t];
    return;
  }
  const int n = bid - 32;
  if (n < 256) {
    const float w1v = W1[t * D_ + n];
    float a = gamma[t] * w1v;
    float b = beta[t] * w1v;
    const float wg = a;
    #pragma unroll
    for (int m = 1; m < 64; m <<= 1) { a += __shfl_xor(a, m); b += __shfl_xor(b, m); }
    if (lane == 0) { ra[wv] = a; rb[wv] = b; }
    __syncthreads();
    const float cs = ra[0] + ra[1] + ra[2] + ra[3];
    if (t == 0) bW1[n] = rb[0] + rb[1] + rb[2] + rb[3] + b1[n];
    const float m = __builtin_fmaf(cs, -1.f / 256.f, wg);
    const __bf16 hi = (__bf16)m;
    const __bf16 lo = (__bf16)(m - (float)hi);
    BT[n * NK + t]       = bits(hi);
    BT[n * NK + 256 + t] = bits(lo);
  } else if (n < 376) {
    const int f = n - 256;
    const float v = frame_emb[f * D_ + t];
    float a = v, b = v * v;
    #pragma unroll
    for (int m = 1; m < 64; m <<= 1) { a += __shfl_xor(a, m); b += __shfl_xor(b, m); }
    if (lane == 0) { ra[wv] = a; rb[wv] = b; }
    __syncthreads();
    if (t == 0) {
      Sfe[f]  = ra[0] + ra[1] + ra[2] + ra[3];
      Sfe2[f] = rb[0] + rb[1] + rb[2] + rb[3];
    }
    const __bf16 hi = (__bf16)v;
    const __bf16 lo = (__bf16)(v - (float)hi);
    BT[n * NK + t]       = bits(hi);
    BT[n * NK + 256 + t] = bits(lo);
  } else if (n < 384) {
    BT[n * NK + t] = 0; BT[n * NK + 256 + t] = 0;
  } else if (n < 400) {
    const int c = n - 384;
    const float v = (c < C_) ? W2[t * C_ + c] : 0.f;
    W2T[c * D_ + t] = bits((__bf16)v);
  } else {
    zerov[t] = 0.f;
  }
}

// ---------- gemmB: PX[MP_ x NN] = A @ B with A built on the fly; Sc/Sc2 in cb==0 ----
__global__ __launch_bounds__(256, 4) void gemmB_kernel(
    const float* __restrict__ base, const float* __restrict__ joint,
    const float* __restrict__ fe, const float* __restrict__ zerov,
    const unsigned short* __restrict__ BT,
    float* __restrict__ PX, unsigned short* __restrict__ P2h,
    float* __restrict__ Sc, float* __restrict__ Sc2) {
  const int tid = threadIdx.x, lane = tid & 63, wave = tid >> 6;
  const int lrow = lane & 15, lgrp = lane >> 4;
  const int rb = blockIdx.x / 6, cb = blockIdx.x % 6;
  const int rowbase = rb * 64 + wave * 16;
  const int colbase = cb * 64;
  const int r = rowbase + lrow;

  const float *p1, *p2;
  if (r < M_) {
    const int b = r / J_, j = r - b * J_;
    p1 = base + b * D_; p2 = joint + j * D_;
  } else if (r < FE0 + F_) {
    p1 = fe + (r - FE0) * D_; p2 = zerov;
  } else {
    p1 = zerov; p2 = zerov;
  }

  const unsigned short* Bp = BT + (size_t)(colbase + lrow) * NK + lgrp * 8;
  f32x4 acc[4] = {};
  float ssum = 0.f, ssq = 0.f;
  #pragma unroll
  for (int s8 = 0; s8 < 8; ++s8) {
    const int k0 = s8 * 32 + lgrp * 8;
    const float4 ca = *(const float4*)(p1 + k0);
    const float4 cb4 = *(const float4*)(p1 + k0 + 4);
    const float4 da = *(const float4*)(p2 + k0);
    const float4 db = *(const float4*)(p2 + k0 + 4);
    const float c[8] = {ca.x + da.x, ca.y + da.y, ca.z + da.z, ca.w + da.w,
                        cb4.x + db.x, cb4.y + db.y, cb4.z + db.z, cb4.w + db.w};
    bf16x8 ahi, alo;
    #pragma unroll
    for (int e = 0; e < 8; ++e) {
      const __bf16 h = (__bf16)c[e];
      ahi[e] = h;
      alo[e] = (__bf16)(c[e] - (float)h);
    }
    if (cb == 0) {
      #pragma unroll
      for (int e = 0; e < 8; ++e) { ssum += c[e]; ssq = __builtin_fmaf(c[e], c[e], ssq); }
    }
    bf16x8 bhi[4], blo[4];
    #pragma unroll
    for (int nf = 0; nf < 4; ++nf) {
      bhi[nf] = *(const bf16x8*)(Bp + (size_t)nf * 16 * NK + s8 * 32);
      blo[nf] = *(const bf16x8*)(Bp + (size_t)nf * 16 * NK + 256 + s8 * 32);
    }
    #pragma unroll
    for (int nf = 0; nf < 4; ++nf)
      acc[nf] = __builtin_amdgcn_mfma_f32_16x16x32_bf16(ahi, bhi[nf], acc[nf], 0, 0, 0);
    #pragma unroll
    for (int nf = 0; nf < 4; ++nf)
      acc[nf] = __builtin_amdgcn_mfma_f32_16x16x32_bf16(alo, bhi[nf], acc[nf], 0, 0, 0);
    #pragma unroll
    for (int nf = 0; nf < 4; ++nf)
      acc[nf] = __builtin_amdgcn_mfma_f32_16x16x32_bf16(ahi, blo[nf], acc[nf], 0, 0, 0);
  }

  if (cb == 0) {
    ssum += __shfl_xor(ssum, 16); ssum += __shfl_xor(ssum, 32);
    ssq  += __shfl_xor(ssq, 16);  ssq  += __shfl_xor(ssq, 32);
    if (lgrp == 0) { Sc[r] = ssum; Sc2[r] = ssq; }
  }

  #pragma unroll
  for (int nf = 0; nf < 4; ++nf)
    #pragma unroll
    for (int r4 = 0; r4 < 4; ++r4) {
      const int orow = rowbase + lgrp * 4 + r4;
      const int ocol = colbase + nf * 16 + lrow;
      const float v = acc[nf][r4];
      PX[(size_t)orow * NN + ocol] = v;
      const int fr = orow - FE0;
      if (fr >= 0 && fr < F_ && ocol < 256)
        P2h[fr * 256 + ocol] = bits((__bf16)v);
    }
}

// ---------- mainC: 2 bj per block; q prefetched to regs; gelu; GEMM2; write ----
__global__ __launch_bounds__(256, 4) void mainC_kernel(
    const float* __restrict__ PX, const unsigned short* __restrict__ P2h,
    const float* __restrict__ bW1,
    const float* __restrict__ Sc, const float* __restrict__ Sc2,
    const float* __restrict__ Sfe, const float* __restrict__ Sfe2,
    const unsigned short* __restrict__ W2T, const float* __restrict__ b2,
    float* __restrict__ out) {
  __shared__ float pc[2][256], bw[256], rstdl[2][128];
  __shared__ __align__(16) unsigned short w2l[4096];   // 16x256 bf16, XOR-swizzled
  __shared__ float outl[16 * 133];
  const int tid = threadIdx.x, lane = tid & 63, wave = tid >> 6;
  const int lrow = lane & 15, lgrp = lane >> 4;
  const int bj0 = blockIdx.x * 2;

  // --- register prefetch of q streams (issued before any barrier) ---
  const int r0 = wave * 32 + lrow, r1 = r0 + 16;
  const int f0 = r0 < F_ ? r0 : F_ - 1;
  const int f1 = r1 < F_ ? r1 : F_ - 1;
  const unsigned short* __restrict__ q0p = P2h + f0 * 256;
  const unsigned short* __restrict__ q1p = P2h + f1 * 256;
  bf16x8 qh0[8], qh1[8];
  #pragma unroll
  for (int s = 0; s < 8; ++s) {
    const int n0 = s * 32 + lgrp * 8;
    qh0[s] = *(const bf16x8*)(q0p + n0);
    qh1[s] = *(const bf16x8*)(q1p + n0);
  }

  #pragma unroll
  for (int q = 0; q < 2; ++q) pc[q][tid] = PX[(size_t)(bj0 + q) * NN + tid];
  bw[tid] = bW1[tid];
  {
    const int r = tid >> 4;
    const int b0 = tid * 32;
    const int sb = b0 ^ ((r & 7) << 4);
    *(uint4*)((char*)w2l + sb)        = *(const uint4*)((const char*)W2T + b0);
    *(uint4*)((char*)w2l + (sb ^ 16)) = *(const uint4*)((const char*)W2T + b0 + 16);
  }
  {
    const int q = tid >> 7;
    const int f = tid & 127;
    const int fc = f < F_ ? f : F_ - 1;
    const float X = PX[(size_t)(bj0 + q) * NN + 256 + fc];
    const float mu = (Sc[bj0 + q] + Sfe[fc]) * (1.f / 256.f);
    const float ms = __builtin_fmaf(2.f, X, Sc2[bj0 + q] + Sfe2[fc]) * (1.f / 256.f);
    rstdl[q][f] = rsqrtf(ms - mu * mu + 1e-5f);
  }
  __syncthreads();

  float rs0[2], rs1[2];
  #pragma unroll
  for (int q = 0; q < 2; ++q) { rs0[q] = rstdl[q][r0]; rs1[q] = rstdl[q][r1]; }

  f32x4 acc[2][2] = {};
  #pragma unroll
  for (int s = 0; s < 8; ++s) {
    const int n0 = s * 32 + lgrp * 8;
    const bf16x8 w2f = *(const bf16x8*)((const char*)w2l +
        ((lrow * 512 + n0 * 2) ^ ((lrow & 7) << 4)));
    float q0f[8], q1f[8], bv[8];
    #pragma unroll
    for (int e = 0; e < 8; ++e) { q0f[e] = (float)qh0[s][e]; q1f[e] = (float)qh1[s][e]; }
    const float4 ba = *(const float4*)(&bw[n0]);
    const float4 bb = *(const float4*)(&bw[n0 + 4]);
    bv[0] = ba.x; bv[1] = ba.y; bv[2] = ba.z; bv[3] = ba.w;
    bv[4] = bb.x; bv[5] = bb.y; bv[6] = bb.z; bv[7] = bb.w;
    #pragma unroll
    for (int q = 0; q < 2; ++q) {
      const float4 pa = *(const float4*)(&pc[q][n0]);
      const float4 pb = *(const float4*)(&pc[q][n0 + 4]);
      const float pv[8] = {pa.x, pa.y, pa.z, pa.w, pb.x, pb.y, pb.z, pb.w};
      bf16x8 af0, af1;
      #pragma unroll
      for (int e = 0; e < 8; ++e) {
        const float u0 = __builtin_fmaf(rs0[q], pv[e] + q0f[e], bv[e]);
        const float u1 = __builtin_fmaf(rs1[q], pv[e] + q1f[e], bv[e]);
        af0[e] = (__bf16)gelu_t(u0);
        af1[e] = (__bf16)gelu_t(u1);
      }
      acc[q][0] = __builtin_amdgcn_mfma_f32_16x16x32_bf16(af0, w2f, acc[q][0], 0, 0, 0);
      acc[q][1] = __builtin_amdgcn_mfma_f32_16x16x32_bf16(af1, w2f, acc[q][1], 0, 0, 0);
    }
  }

  #pragma unroll
  for (int q = 0; q < 2; ++q) {
    #pragma unroll
    for (int mf = 0; mf < 2; ++mf)
      #pragma unroll
      for (int r4 = 0; r4 < 4; ++r4) {
        const int frow = wave * 32 + mf * 16 + lgrp * 4 + r4;
        outl[lrow * 133 + frow] = acc[q][mf][r4];
      }
    __syncthreads();
    const int obase = (bj0 + q) * C_ * F_;
    for (int idx = tid; idx < C_ * F_; idx += 256) {
      const int c = idx / F_;
      const int f = idx - c * F_;
      out[obase + idx] = outl[c * 133 + f] + b2[c];
    }
    __syncthreads();
  }
}

extern "C" void kernel_launch(void* const* d_in, const int* in_sizes, int n_in,
                              void* d_out, int out_size, void* d_ws, size_t ws_size,
                              hipStream_t stream) {
  const float* z         = (const float*)d_in[0];
  const float* W_latent  = (const float*)d_in[1];
  const float* b_latent  = (const float*)d_in[2];
  const float* joint_emb = (const float*)d_in[3];
  const float* frame_emb = (const float*)d_in[4];
  const float* ln_g      = (const float*)d_in[5];
  const float* ln_b      = (const float*)d_in[6];
  const float* W1        = (const float*)d_in[7];
  const float* b1        = (const float*)d_in[8];
  const float* W2        = (const float*)d_in[9];
  const float* b2        = (const float*)d_in[10];
  float* out = (float*)d_out;

  char* ws = (char*)d_ws;
  float*          base  = (float*)(ws + 0);              // 32 KB
  unsigned short* W2T   = (unsigned short*)(ws + 32768); // 8 KB
  float*          bW1   = (float*)(ws + 40960);          // 1 KB
  float*          Sfe   = (float*)(ws + 41984);          // 0.5 KB
  float*          Sfe2  = (float*)(ws + 42496);          // 0.5 KB
  float*          Sc    = (float*)(ws + 43008);          // 18.5 KB
  float*          Sc2   = (float*)(ws + 61952);          // 18.5 KB
  float*          zerov = (float*)(ws + 80896);          // 1 KB
  unsigned short* BT    = (unsigned short*)(ws + 81920); // 384 KB
  unsigned short* P2h   = (unsigned short*)(ws + 700416);// 60 KB
  float*          PX    = (float*)(ws + 8388608);        // 7.0 MB

  prepAll_kernel<<<433, 256, 0, stream>>>(z, W_latent, b_latent, W1, ln_g, ln_b, b1,
                                          frame_emb, W2, base, BT, bW1, Sfe, Sfe2,
                                          W2T, zerov);
  gemmB_kernel<<<444, 256, 0, stream>>>(base, joint_emb, frame_emb, zerov, BT,
                                        PX, P2h, Sc, Sc2);
  mainC_kernel<<<M_ / 2, 256, 0, stream>>>(PX, P2h, bW1, Sc, Sc2, Sfe, Sfe2, W2T, b2, out);
}